// Round 8
// baseline (181.035 us; speedup 1.0000x reference)
//
#include <hip/hip_runtime.h>
#include <math.h>

// Volume dims (fixed by the problem: IMG_SHAPE = (256,256,256))
#define DD 256
#define HH 256
#define WW 256
#define TI 16          // output tile extent in i
#define TJ 8           // output tile extent in j
#define TK 16          // output tile extent in k
#define NT 4           // i-consecutive tiles per block (pipelined)
#define LDSF 8192      // LDS floats for staged input box (32 KB)

typedef float f2v __attribute__((ext_vector_type(2)));
typedef f2v __attribute__((aligned(4))) f2u;
typedef float f4v __attribute__((ext_vector_type(4)));
typedef f4v __attribute__((aligned(4))) f4u;

// ---------------------------------------------------------------------------
// Kernel 1: one thread computes the 3x4 resampling transform
// T = rows 0..2 of inv(flo_v2r) @ T_rig @ ref_v2r -> 12 floats in d_ws.
// ---------------------------------------------------------------------------
__global__ void compute_T_kernel(const float* __restrict__ angle,
                                 const float* __restrict__ trans,
                                 const float* __restrict__ ref_v2r,
                                 const float* __restrict__ flo_v2r,
                                 const float* __restrict__ cog,
                                 float* __restrict__ Tout /* 12 floats */) {
    if (blockIdx.x != 0 || threadIdx.x != 0) return;

    const float ax = angle[0], ay = angle[1], az = angle[2];
    const float cx = cosf(ax), sx = sinf(ax);
    const float cy = cosf(ay), sy = sinf(ay);
    const float cz = cosf(az), sz = sinf(az);

    // R = Rx @ Ry @ Rz ;  Rx@Ry = [[cy,0,sy],[sx*sy,cx,-sx*cy],[-cx*sy,sx,cx*cy]]
    float R[3][3];
    const float a00 = cy,       a01 = 0.0f, a02 = sy;
    const float a10 = sx * sy,  a11 = cx,   a12 = -sx * cy;
    const float a20 = -cx * sy, a21 = sx,   a22 = cx * cy;
    R[0][0] = a00 * cz + a01 * sz; R[0][1] = -a00 * sz + a01 * cz; R[0][2] = a02;
    R[1][0] = a10 * cz + a11 * sz; R[1][1] = -a10 * sz + a11 * cz; R[1][2] = a12;
    R[2][0] = a20 * cz + a21 * sz; R[2][1] = -a20 * sz + a21 * cz; R[2][2] = a22;

    // T_rig: linear part R, translation cog + t - R@cog
    float Trig[4][4];
    for (int r = 0; r < 4; ++r)
        for (int c = 0; c < 4; ++c)
            Trig[r][c] = (r == c) ? 1.0f : 0.0f;
    for (int r = 0; r < 3; ++r) {
        for (int c = 0; c < 3; ++c) Trig[r][c] = R[r][c];
        Trig[r][3] = cog[r] + trans[r]
                   - (R[r][0] * cog[0] + R[r][1] * cog[1] + R[r][2] * cog[2]);
    }

    // Closed-form 4x4 inverse of flo_v2r (adjugate).
    float m[16], inv[16];
    for (int q = 0; q < 16; ++q) m[q] = flo_v2r[q];
    inv[0]  =  m[5]*m[10]*m[15] - m[5]*m[11]*m[14] - m[9]*m[6]*m[15]
             + m[9]*m[7]*m[14] + m[13]*m[6]*m[11] - m[13]*m[7]*m[10];
    inv[4]  = -m[4]*m[10]*m[15] + m[4]*m[11]*m[14] + m[8]*m[6]*m[15]
             - m[8]*m[7]*m[14] - m[12]*m[6]*m[11] + m[12]*m[7]*m[10];
    inv[8]  =  m[4]*m[9]*m[15] - m[4]*m[11]*m[13] - m[8]*m[5]*m[15]
             + m[8]*m[7]*m[13] + m[12]*m[5]*m[11] - m[12]*m[7]*m[9];
    inv[12] = -m[4]*m[9]*m[14] + m[4]*m[10]*m[13] + m[8]*m[5]*m[14]
             - m[8]*m[6]*m[13] - m[12]*m[5]*m[10] + m[12]*m[6]*m[9];
    inv[1]  = -m[1]*m[10]*m[15] + m[1]*m[11]*m[14] + m[9]*m[2]*m[15]
             - m[9]*m[3]*m[14] - m[13]*m[2]*m[11] + m[13]*m[3]*m[10];
    inv[5]  =  m[0]*m[10]*m[15] - m[0]*m[11]*m[14] - m[8]*m[2]*m[15]
             + m[8]*m[3]*m[14] + m[12]*m[2]*m[11] - m[12]*m[3]*m[10];
    inv[9]  = -m[0]*m[9]*m[15] + m[0]*m[11]*m[13] + m[8]*m[1]*m[15]
             - m[8]*m[3]*m[13] - m[12]*m[1]*m[11] + m[12]*m[3]*m[9];
    inv[13] =  m[0]*m[9]*m[14] - m[0]*m[10]*m[13] - m[8]*m[1]*m[14]
             + m[8]*m[2]*m[13] + m[12]*m[1]*m[10] - m[12]*m[2]*m[9];
    inv[2]  =  m[1]*m[6]*m[15] - m[1]*m[7]*m[14] - m[5]*m[2]*m[15]
             + m[5]*m[3]*m[14] + m[13]*m[2]*m[7] - m[13]*m[3]*m[6];
    inv[6]  = -m[0]*m[6]*m[15] + m[0]*m[7]*m[14] + m[4]*m[2]*m[15]
             - m[4]*m[3]*m[14] - m[12]*m[2]*m[7] + m[12]*m[3]*m[6];
    inv[10] =  m[0]*m[5]*m[15] - m[0]*m[7]*m[13] - m[4]*m[1]*m[15]
             + m[4]*m[3]*m[13] + m[12]*m[1]*m[7] - m[12]*m[3]*m[5];
    inv[14] = -m[0]*m[5]*m[14] + m[0]*m[6]*m[13] + m[4]*m[1]*m[14]
             - m[4]*m[2]*m[13] - m[12]*m[1]*m[6] + m[12]*m[2]*m[5];
    inv[3]  = -m[1]*m[6]*m[11] + m[1]*m[7]*m[10] + m[5]*m[2]*m[11]
             - m[5]*m[3]*m[10] - m[9]*m[2]*m[7] + m[9]*m[3]*m[6];
    inv[7]  =  m[0]*m[6]*m[11] - m[0]*m[7]*m[10] - m[4]*m[2]*m[11]
             + m[4]*m[3]*m[10] + m[8]*m[2]*m[7] - m[8]*m[3]*m[6];
    inv[11] = -m[0]*m[5]*m[11] + m[0]*m[7]*m[9] + m[4]*m[1]*m[11]
             - m[4]*m[3]*m[9] - m[8]*m[1]*m[7] + m[8]*m[3]*m[5];
    inv[15] =  m[0]*m[5]*m[10] - m[0]*m[6]*m[9] - m[4]*m[1]*m[10]
             + m[4]*m[2]*m[9] + m[8]*m[1]*m[6] - m[8]*m[2]*m[5];
    const float det = m[0]*inv[0] + m[1]*inv[4] + m[2]*inv[8] + m[3]*inv[12];
    const float rdet = 1.0f / det;

    // M1 = Trig @ ref_v2r ; T = invF @ M1 ; rows 0..2 out
    float M1[4][4];
    for (int r = 0; r < 4; ++r)
        for (int c = 0; c < 4; ++c) {
            float s = 0.0f;
            for (int q = 0; q < 4; ++q) s += Trig[r][q] * ref_v2r[q * 4 + c];
            M1[r][c] = s;
        }
    for (int r = 0; r < 3; ++r)
        for (int c = 0; c < 4; ++c) {
            float s = 0.0f;
            for (int q = 0; q < 4; ++q) s += (inv[r * 4 + q] * rdet) * M1[q][c];
            Tout[r * 4 + c] = s;
        }
}

// ---------------------------------------------------------------------------
// Kernel 2: trilinear warp via LDS-staged tiles, v3: multi-tile pipelined.
//
// R5-R11: global-gather floor ~88-109us (TA address-rate wall, 4 gathers/vox).
// R12: LDS tiles v1: 131us (9.1M bank-conflict cy, 2 blocks/CU, no overlap).
// R13: pitched rows + 32KB: 97us steady. Conflicts 2.2M (~4us), VALU 33%,
//      LDS ~18us -> pipes sum << 97: the rest is per-block stage latency +
//      barrier serialization with only ~2.5 resident blocks to cover it.
// R14 (this): hide the stage under the consume (T14 async-STAGE split).
//      Block owns NT=4 i-consecutive tiles. Per iteration:
//        stage_load(t+1) -> regs   (8 dwordx4, coalesced, latency hidden)
//        consume(t) from LDS       (long VALU+ds phase)
//        pin regs (R7 mechanism)   (forces loads issued before, done by now)
//        barrier; ds_write(t+1); barrier
//      Single 32KB buffer.  Chunk->(li,lj,kk) via two small-divisor float
//      divides (margins: err/margin < 0.01 for all Pk; Sj<=16 enforced by
//      fits).  Staged loads/writes lane-contiguous (conflict-free).  Box
//      math, pitch, and consume arithmetic VERBATIM R13 -> bit-exact.
//      Per-tile fits guard -> verbatim global-gather fallback; barriers
//      stay block-uniform.
// ---------------------------------------------------------------------------
struct BoxT {
    int lo_i, lo_j, lo_k;
    int Si, Sj, Pk, SkL, SjPk, total;
    bool fits;
};

__global__ __launch_bounds__(256) void warp_kernel(
        const float* __restrict__ vol,
        const float* __restrict__ T,
        float* __restrict__ out) {
    // Wave-uniform scalar loads of the transform.
    const float t0 = T[0],  t1 = T[1],  t2  = T[2],  t3  = T[3];
    const float t4 = T[4],  t5 = T[5],  t6  = T[6],  t7  = T[7];
    const float t8 = T[8],  t9 = T[9],  t10 = T[10], t11 = T[11];

    // XCD brick mapping: xcd -> 2x2x2 brick of 128^3.
    // Per brick: 2 i-quads(64) x 16 j-tiles(8) x 8 k-tiles(16) = 256 blocks.
    const int bid = blockIdx.x;
    const int xcd = bid & 7;
    const int n = bid >> 3;              // 0..255 per brick
    const int bi = (xcd >> 2) & 1;
    const int bj = (xcd >> 1) & 1;
    const int bk = xcd & 1;
    const int kt = n & 7;
    const int jt = (n >> 3) & 15;
    const int iq = (n >> 7) & 1;

    const int i0q = (bi << 7) + (iq << 6);   // 64-i quad base
    const int j0  = (bj << 7) + (jt << 3);
    const int k0  = (bk << 7) + (kt << 4);

    const int tid = threadIdx.x;
    const int kl = tid & 15;             // k within tile
    const int jl = (tid >> 4) & 7;       // j within tile
    const int ihalf = tid >> 7;          // 0/1: i sub-block of 8
    const int j = j0 + jl;
    const int k = k0 + kl;
    const float gj = (float)j, gk = (float)k;

    __shared__ __align__(16) float sv[LDSF];

    // ---- bbox of one 16x8x16 tile (verbatim R13 math) ----------------------
    auto mkbox = [&](int i0t) -> BoxT {
        float mni =  1e30f, mxi = -1e30f;
        float mnj =  1e30f, mxj = -1e30f;
        float mnk =  1e30f, mxk = -1e30f;
#pragma unroll
        for (int c = 0; c < 8; ++c) {
            const float ci_ = (float)(i0t + ((c & 1) ? (TI - 1) : 0));
            const float cj_ = (float)(j0 + ((c & 2) ? (TJ - 1) : 0));
            const float ck_ = (float)(k0 + ((c & 4) ? (TK - 1) : 0));
            const float di = t0 * ci_ + t1 * cj_ + t2  * ck_ + t3;
            const float dj = t4 * ci_ + t5 * cj_ + t6  * ck_ + t7;
            const float dk = t8 * ci_ + t9 * cj_ + t10 * ck_ + t11;
            mni = fminf(mni, di); mxi = fmaxf(mxi, di);
            mnj = fminf(mnj, dj); mxj = fmaxf(mxj, dj);
            mnk = fminf(mnk, dk); mxk = fmaxf(mxk, dk);
        }
        int lo_i = (int)fminf(fmaxf(mni, 0.0f), 255.0f);
        int hi_i = (int)fminf(fmaxf(mxi, 0.0f), 255.0f);
        int lo_j = (int)fminf(fmaxf(mnj, 0.0f), 255.0f);
        int hi_j = (int)fminf(fmaxf(mxj, 0.0f), 255.0f);
        int lo_k = (int)fminf(fmaxf(mnk, 0.0f), 255.0f);
        int hi_k = (int)fminf(fmaxf(mxk, 0.0f), 255.0f);
        lo_i = min(max(lo_i - 1, 0), 252);
        lo_j = min(max(lo_j - 1, 0), 252);
        lo_k = min(max(lo_k - 1, 0), 252);
        hi_i = min(max(hi_i + 2, lo_i + 3), 255);
        hi_j = min(max(hi_j + 2, lo_j + 3), 255);
        hi_k = min(max(hi_k + 2, lo_k + 3), 255);
        BoxT B;
        B.Si = hi_i - lo_i + 1;
        B.Sj = hi_j - lo_j + 1;
        int Sk  = hi_k - lo_k + 1;
        int SkL = (Sk + 3) & ~3;
        if (lo_k + SkL > 256) {          // k-window shift guard (R13)
            lo_k = 256 - SkL;
            Sk = hi_k - lo_k + 1;
            SkL = (Sk + 3) & ~3;
        }
        int Pk = SkL;
        if ((Pk & 7) == 0) Pk += 4;      // Pk == 4 (mod 8)
        B.lo_i = lo_i; B.lo_j = lo_j; B.lo_k = lo_k;
        B.Pk = Pk; B.SkL = SkL;
        B.SjPk = B.Sj * Pk;
        B.total = B.Si * B.SjPk;
        B.fits = (B.total <= LDSF) && (B.Sj <= 16);
        return B;
    };

    f4v r[8];   // staging payload: 8 chunks x 16B (unrolled static indexing)

    // Issue the 8 coalesced chunk loads for box B into r[] (no LDS touch).
    auto stage_load = [&](const BoxT& B) {
        const float invPk = 1.0f / (float)B.Pk;
        const float invSj = 1.0f / (float)B.Sj;
#pragma unroll
        for (int q = 0; q < 8; ++q) {
            int fl = (tid << 2) + (q << 10);       // (tid + 256q)*4
            fl = min(fl, B.total - 4);             // clamp (dup tail, unused)
            const float ff = (float)fl + 0.5f;
            const int rowid = (int)(ff * invPk);   // exact floor(fl/Pk)
            const int kk = fl - rowid * B.Pk;
            const float fr = (float)rowid + 0.5f;
            const int li = (int)(fr * invSj);      // exact floor(rowid/Sj)
            const int lj = rowid - li * B.Sj;
            const int kkg = min(kk, B.SkL - 4);    // row-pad clamp (safe addr)
            const float* gp = vol + ((B.lo_i + li) << 16)
                                  + ((B.lo_j + lj) << 8) + (B.lo_k + kkg);
            r[q] = *(const f4u*)gp;
        }
    };

    // Write r[] to LDS at the flat pitched offsets (lane-contiguous).
    auto stage_write = [&]() {
#pragma unroll
        for (int q = 0; q < 8; ++q) {
            const int fl = (tid << 2) + (q << 10);
            *(f4u*)(sv + fl) = r[q];
        }
    };

    // Consume one tile from LDS (verbatim R13 arithmetic -> bit-exact).
    auto consume_lds = [&](const BoxT& B, int i0t) {
        const int ob = (i0t << 16) + (j << 8) + k;
#pragma unroll
        for (int IT = 0; IT < 2; ++IT) {
            const float gi_ = (float)(i0t + ihalf * 8 + IT * 4);
            float di_ = t0 * gi_ + t1 * gj + t2  * gk + t3;
            float dj_ = t4 * gi_ + t5 * gj + t6  * gk + t7;
            float dk_ = t8 * gi_ + t9 * gj + t10 * gk + t11;
#pragma unroll
            for (int s_ = 0; s_ < 4; ++s_) {
                const float cdi = fminf(fmaxf(di_, 0.0f), (float)(DD - 1));
                const float cdj = fminf(fmaxf(dj_, 0.0f), (float)(HH - 1));
                const float cdk = fminf(fmaxf(dk_, 0.0f), (float)(WW - 1));
                const int fi = (int)cdi;
                const int fj = (int)cdj;
                const int fk = (int)cdk;
                const int ci = min(fi + 1, DD - 1);
                const int cj = min(fj + 1, HH - 1);
                const int pk = min(fk, WW - 2);
                const float wi = cdi - (float)fi;
                const float wj = cdj - (float)fj;
                const float wk = cdk - (float)pk;
                const bool ok_ = (di_ >= 0.0f) & (di_ <= (float)(DD - 1)) &
                                 (dj_ >= 0.0f) & (dj_ <= (float)(HH - 1)) &
                                 (dk_ >= 0.0f) & (dk_ <= (float)(WW - 1));

                const int o_fi = (fi - B.lo_i) * B.SjPk;
                const int o_ci = (ci - B.lo_i) * B.SjPk;
                const int o_fj = (fj - B.lo_j) * B.Pk;
                const int o_cj = (cj - B.lo_j) * B.Pk;
                const int pl = pk - B.lo_k;

                const f2v v0 = *(const f2u*)(sv + o_fi + o_fj + pl);
                const f2v v1 = *(const f2u*)(sv + o_fi + o_cj + pl);
                const f2v v2 = *(const f2u*)(sv + o_ci + o_fj + pl);
                const f2v v3 = *(const f2u*)(sv + o_ci + o_cj + pl);

                const float c00 = v0.x + (v0.y - v0.x) * wk;
                const float c01 = v1.x + (v1.y - v1.x) * wk;
                const float c10 = v2.x + (v2.y - v2.x) * wk;
                const float c11 = v3.x + (v3.y - v3.x) * wk;
                const float c0  = c00 + (c01 - c00) * wj;
                const float c1  = c10 + (c11 - c10) * wj;
                const float val = c0 + (c1 - c0) * wi;

                __builtin_nontemporal_store(ok_ ? val : 0.0f,
                    &out[ob + ((ihalf * 8 + IT * 4 + s_) << 16)]);

                di_ += t0; dj_ += t4; dk_ += t8;
            }
        }
    };

    // Fallback: per-voxel global gather (verbatim R13).
    auto consume_glob = [&](int i0t) {
        const int ob = (i0t << 16) + (j << 8) + k;
#pragma unroll
        for (int IT = 0; IT < 2; ++IT) {
            const float gi_ = (float)(i0t + ihalf * 8 + IT * 4);
            float di_ = t0 * gi_ + t1 * gj + t2  * gk + t3;
            float dj_ = t4 * gi_ + t5 * gj + t6  * gk + t7;
            float dk_ = t8 * gi_ + t9 * gj + t10 * gk + t11;
#pragma unroll
            for (int s_ = 0; s_ < 4; ++s_) {
                const float cdi = fminf(fmaxf(di_, 0.0f), (float)(DD - 1));
                const float cdj = fminf(fmaxf(dj_, 0.0f), (float)(HH - 1));
                const float cdk = fminf(fmaxf(dk_, 0.0f), (float)(WW - 1));
                const int fi = (int)cdi;
                const int fj = (int)cdj;
                const int fk = (int)cdk;
                const int ci = min(fi + 1, DD - 1);
                const int cj = min(fj + 1, HH - 1);
                const int pk = min(fk, WW - 2);
                const float wi = cdi - (float)fi;
                const float wj = cdj - (float)fj;
                const float wk = cdk - (float)pk;
                const bool ok_ = (di_ >= 0.0f) & (di_ <= (float)(DD - 1)) &
                                 (dj_ >= 0.0f) & (dj_ <= (float)(HH - 1)) &
                                 (dk_ >= 0.0f) & (dk_ <= (float)(WW - 1));

                const int fi_o = fi << 16, ci_o = ci << 16;
                const int fj_o = fj << 8,  cj_o = cj << 8;
                const f2v v0 = *(const f2u*)(vol + (fi_o + fj_o + pk));
                const f2v v1 = *(const f2u*)(vol + (fi_o + cj_o + pk));
                const f2v v2 = *(const f2u*)(vol + (ci_o + fj_o + pk));
                const f2v v3 = *(const f2u*)(vol + (ci_o + cj_o + pk));

                const float c00 = v0.x + (v0.y - v0.x) * wk;
                const float c01 = v1.x + (v1.y - v1.x) * wk;
                const float c10 = v2.x + (v2.y - v2.x) * wk;
                const float c11 = v3.x + (v3.y - v3.x) * wk;
                const float c0  = c00 + (c01 - c00) * wj;
                const float c1  = c10 + (c11 - c10) * wj;
                const float val = c0 + (c1 - c0) * wi;

                __builtin_nontemporal_store(ok_ ? val : 0.0f,
                    &out[ob + ((ihalf * 8 + IT * 4 + s_) << 16)]);

                di_ += t0; dj_ += t4; dk_ += t8;
            }
        }
    };

    // ---------------- pipelined NT-tile main loop ---------------------------
    BoxT Bc = mkbox(i0q);
    if (Bc.fits) { stage_load(Bc); stage_write(); }   // prologue (vmcnt auto)
    __syncthreads();

#pragma unroll
    for (int t = 0; t < NT; ++t) {
        const int i0t = i0q + (t << 4);
        BoxT Bn;
        if (t + 1 < NT) {
            Bn = mkbox(i0q + ((t + 1) << 4));
            if (Bn.fits) {
                stage_load(Bn);                       // issue early
                __builtin_amdgcn_sched_barrier(0);    // ...before consume
            }
        }
        if (Bc.fits) consume_lds(Bc, i0t);
        else         consume_glob(i0t);
        if (t + 1 < NT) {
            if (Bn.fits) {
                // Pin: loads must be complete here (hidden under consume).
                __builtin_amdgcn_sched_barrier(0);
#pragma unroll
                for (int q = 0; q < 8; ++q) asm volatile("" : "+v"(r[q]));
                __builtin_amdgcn_sched_barrier(0);
            }
            __syncthreads();                          // done reading tile t
            if (Bn.fits) stage_write();
            __syncthreads();                          // tile t+1 visible
            Bc = Bn;
        }
    }
}

extern "C" void kernel_launch(void* const* d_in, const int* in_sizes, int n_in,
                              void* d_out, int out_size, void* d_ws, size_t ws_size,
                              hipStream_t stream) {
    const float* image_targ  = (const float*)d_in[0];
    const float* angle       = (const float*)d_in[1];
    const float* translation = (const float*)d_in[2];
    const float* ref_v2r     = (const float*)d_in[3];
    const float* flo_v2r     = (const float*)d_in[4];
    const float* cog         = (const float*)d_in[5];
    float* out = (float*)d_out;
    float* Tws = (float*)d_ws;   // 12 floats

    compute_T_kernel<<<1, 64, 0, stream>>>(angle, translation, ref_v2r,
                                           flo_v2r, cog, Tws);
    // 2048 blocks: 8 bricks x (2 i-quads x 16 j-tiles x 8 k-tiles).
    warp_kernel<<<2048, 256, 0, stream>>>(image_targ, Tws, out);
}

// Round 9
// 174.064 us; speedup vs baseline: 1.0401x; 1.0401x over previous
//
#include <hip/hip_runtime.h>
#include <math.h>

// Volume dims (fixed by the problem: IMG_SHAPE = (256,256,256))
#define DD 256
#define HH 256
#define WW 256
#define TI 8           // output tile extent in i   [R15: 16 -> 8]
#define TJ 8           // output tile extent in j
#define TK 16          // output tile extent in k
#define LDSF 5120      // LDS floats (20 KB -> 8 blocks/CU)

typedef float f2v __attribute__((ext_vector_type(2)));
typedef f2v __attribute__((aligned(4))) f2u;
typedef float f4v __attribute__((ext_vector_type(4)));
typedef f4v __attribute__((aligned(4))) f4u;

// ---------------------------------------------------------------------------
// Kernel 1: one thread computes the 3x4 resampling transform
// T = rows 0..2 of inv(flo_v2r) @ T_rig @ ref_v2r -> 12 floats in d_ws.
// ---------------------------------------------------------------------------
__global__ void compute_T_kernel(const float* __restrict__ angle,
                                 const float* __restrict__ trans,
                                 const float* __restrict__ ref_v2r,
                                 const float* __restrict__ flo_v2r,
                                 const float* __restrict__ cog,
                                 float* __restrict__ Tout /* 12 floats */) {
    if (blockIdx.x != 0 || threadIdx.x != 0) return;

    const float ax = angle[0], ay = angle[1], az = angle[2];
    const float cx = cosf(ax), sx = sinf(ax);
    const float cy = cosf(ay), sy = sinf(ay);
    const float cz = cosf(az), sz = sinf(az);

    // R = Rx @ Ry @ Rz ;  Rx@Ry = [[cy,0,sy],[sx*sy,cx,-sx*cy],[-cx*sy,sx,cx*cy]]
    float R[3][3];
    const float a00 = cy,       a01 = 0.0f, a02 = sy;
    const float a10 = sx * sy,  a11 = cx,   a12 = -sx * cy;
    const float a20 = -cx * sy, a21 = sx,   a22 = cx * cy;
    R[0][0] = a00 * cz + a01 * sz; R[0][1] = -a00 * sz + a01 * cz; R[0][2] = a02;
    R[1][0] = a10 * cz + a11 * sz; R[1][1] = -a10 * sz + a11 * cz; R[1][2] = a12;
    R[2][0] = a20 * cz + a21 * sz; R[2][1] = -a20 * sz + a21 * cz; R[2][2] = a22;

    // T_rig: linear part R, translation cog + t - R@cog
    float Trig[4][4];
    for (int r = 0; r < 4; ++r)
        for (int c = 0; c < 4; ++c)
            Trig[r][c] = (r == c) ? 1.0f : 0.0f;
    for (int r = 0; r < 3; ++r) {
        for (int c = 0; c < 3; ++c) Trig[r][c] = R[r][c];
        Trig[r][3] = cog[r] + trans[r]
                   - (R[r][0] * cog[0] + R[r][1] * cog[1] + R[r][2] * cog[2]);
    }

    // Closed-form 4x4 inverse of flo_v2r (adjugate).
    float m[16], inv[16];
    for (int q = 0; q < 16; ++q) m[q] = flo_v2r[q];
    inv[0]  =  m[5]*m[10]*m[15] - m[5]*m[11]*m[14] - m[9]*m[6]*m[15]
             + m[9]*m[7]*m[14] + m[13]*m[6]*m[11] - m[13]*m[7]*m[10];
    inv[4]  = -m[4]*m[10]*m[15] + m[4]*m[11]*m[14] + m[8]*m[6]*m[15]
             - m[8]*m[7]*m[14] - m[12]*m[6]*m[11] + m[12]*m[7]*m[10];
    inv[8]  =  m[4]*m[9]*m[15] - m[4]*m[11]*m[13] - m[8]*m[5]*m[15]
             + m[8]*m[7]*m[13] + m[12]*m[5]*m[11] - m[12]*m[7]*m[9];
    inv[12] = -m[4]*m[9]*m[14] + m[4]*m[10]*m[13] + m[8]*m[5]*m[14]
             - m[8]*m[6]*m[13] - m[12]*m[5]*m[10] + m[12]*m[6]*m[9];
    inv[1]  = -m[1]*m[10]*m[15] + m[1]*m[11]*m[14] + m[9]*m[2]*m[15]
             - m[9]*m[3]*m[14] - m[13]*m[2]*m[11] + m[13]*m[3]*m[10];
    inv[5]  =  m[0]*m[10]*m[15] - m[0]*m[11]*m[14] - m[8]*m[2]*m[15]
             + m[8]*m[3]*m[14] + m[12]*m[2]*m[11] - m[12]*m[3]*m[10];
    inv[9]  = -m[0]*m[9]*m[15] + m[0]*m[11]*m[13] + m[8]*m[1]*m[15]
             - m[8]*m[3]*m[13] - m[12]*m[1]*m[11] + m[12]*m[3]*m[9];
    inv[13] =  m[0]*m[9]*m[14] - m[0]*m[10]*m[13] - m[8]*m[1]*m[14]
             + m[8]*m[2]*m[13] + m[12]*m[1]*m[10] - m[12]*m[2]*m[9];
    inv[2]  =  m[1]*m[6]*m[15] - m[1]*m[7]*m[14] - m[5]*m[2]*m[15]
             + m[5]*m[3]*m[14] + m[13]*m[2]*m[7] - m[13]*m[3]*m[6];
    inv[6]  = -m[0]*m[6]*m[15] + m[0]*m[7]*m[14] + m[4]*m[2]*m[15]
             - m[4]*m[3]*m[14] - m[12]*m[2]*m[7] + m[12]*m[3]*m[6];
    inv[10] =  m[0]*m[5]*m[15] - m[0]*m[7]*m[13] - m[4]*m[1]*m[15]
             + m[4]*m[3]*m[13] + m[12]*m[1]*m[7] - m[12]*m[3]*m[5];
    inv[14] = -m[0]*m[5]*m[14] + m[0]*m[6]*m[13] + m[4]*m[1]*m[14]
             - m[4]*m[2]*m[13] - m[12]*m[1]*m[6] + m[12]*m[2]*m[5];
    inv[3]  = -m[1]*m[6]*m[11] + m[1]*m[7]*m[10] + m[5]*m[2]*m[11]
             - m[5]*m[3]*m[10] - m[9]*m[2]*m[7] + m[9]*m[3]*m[6];
    inv[7]  =  m[0]*m[6]*m[11] - m[0]*m[7]*m[10] - m[4]*m[2]*m[11]
             + m[4]*m[3]*m[10] + m[8]*m[2]*m[7] - m[8]*m[3]*m[6];
    inv[11] = -m[0]*m[5]*m[11] + m[0]*m[7]*m[9] + m[4]*m[1]*m[11]
             - m[4]*m[3]*m[9] - m[8]*m[1]*m[7] + m[8]*m[3]*m[5];
    inv[15] =  m[0]*m[5]*m[10] - m[0]*m[6]*m[9] - m[4]*m[1]*m[10]
             + m[4]*m[2]*m[9] + m[8]*m[1]*m[6] - m[8]*m[2]*m[5];
    const float det = m[0]*inv[0] + m[1]*inv[4] + m[2]*inv[8] + m[3]*inv[12];
    const float rdet = 1.0f / det;

    // M1 = Trig @ ref_v2r ; T = invF @ M1 ; rows 0..2 out
    float M1[4][4];
    for (int r = 0; r < 4; ++r)
        for (int c = 0; c < 4; ++c) {
            float s = 0.0f;
            for (int q = 0; q < 4; ++q) s += Trig[r][q] * ref_v2r[q * 4 + c];
            M1[r][c] = s;
        }
    for (int r = 0; r < 3; ++r)
        for (int c = 0; c < 4; ++c) {
            float s = 0.0f;
            for (int q = 0; q < 4; ++q) s += (inv[r * 4 + q] * rdet) * M1[q][c];
            Tout[r * 4 + c] = s;
        }
}

// ---------------------------------------------------------------------------
// Kernel 2: trilinear warp via LDS-staged tiles, v4.
//
// R12: LDS tiles, 64KB, 2 blocks/CU: 131us (9.1M conflict cy, no overlap).
// R13: 16x8x16, 32KB pitched: 97us. Pipes sum ~65us; gap = stage latency +
//      barrier with only ~2.5 resident blocks/CU to cover it.
// R14: intra-block NT=4 pipeline: 110us. REGRESSED - bookkeeping (per-tile
//      block-redundant bbox, float-div chunk addressing, 2 extra barriers
//      per tile, payload pinned across consume) cost more than the hidden
//      latency. Lesson: buy overlap with RESIDENT BLOCKS, not intra-block
//      pipelining (m114: wave-level overlap is free).
// R15 (this): R13 structure, tile 8i x 8j x 16k, LDSF 5120 (20KB) ->
//      8 blocks/CU co-resident (VGPR<=64 keeps wave cap). Halo ratio
//      unchanged (~3.4 staged floats/voxel). Grid 16384. Plus a
//      block-uniform INTERIOR fast path: if all 8 bbox corners lie in
//      [0.5, 253.5]^3, clamps can't engage and ok==true (margin 1.0 >>
//      1e-4 incremental drift) -> skip clamps/ok/min (17 of ~45 VALU
//      ops/voxel), values bit-identical. Edge tiles + fallback verbatim R13.
// ---------------------------------------------------------------------------
__global__ __launch_bounds__(256) void warp_kernel(
        const float* __restrict__ vol,
        const float* __restrict__ T,
        float* __restrict__ out) {
    // Wave-uniform scalar loads of the transform.
    const float t0 = T[0],  t1 = T[1],  t2  = T[2],  t3  = T[3];
    const float t4 = T[4],  t5 = T[5],  t6  = T[6],  t7  = T[7];
    const float t8 = T[8],  t9 = T[9],  t10 = T[10], t11 = T[11];

    // XCD brick mapping: xcd -> 2x2x2 brick of 128^3.
    // Per brick: 16 i-tiles(8) x 16 j-tiles(8) x 8 k-tiles(16) = 2048 blocks.
    const int bid = blockIdx.x;
    const int xcd = bid & 7;
    const int n = bid >> 3;              // 0..2047 per brick
    const int bi = (xcd >> 2) & 1;
    const int bj = (xcd >> 1) & 1;
    const int bk = xcd & 1;
    const int kt = n & 7;
    const int jt = (n >> 3) & 15;
    const int it = n >> 7;               // 0..15

    const int i0 = (bi << 7) + (it << 3);
    const int j0 = (bj << 7) + (jt << 3);
    const int k0 = (bk << 7) + (kt << 4);

    const int tid = threadIdx.x;
    const int kl = tid & 15;             // k within tile
    const int jl = (tid >> 4) & 7;       // j within tile
    const int ihalf = tid >> 7;          // 0/1: i sub-block of 4
    const int j = j0 + jl;
    const int k = k0 + kl;
    const float gj = (float)j, gk = (float)k;
    const int out_base = (i0 << 16) + (j << 8) + k;

    __shared__ __align__(16) float sv[LDSF];

    // ---- input bbox of this tile (verbatim R13 math, TI=8) -----------------
    float mni =  1e30f, mxi = -1e30f;
    float mnj =  1e30f, mxj = -1e30f;
    float mnk =  1e30f, mxk = -1e30f;
#pragma unroll
    for (int c = 0; c < 8; ++c) {
        const float ci_ = (float)(i0 + ((c & 1) ? (TI - 1) : 0));
        const float cj_ = (float)(j0 + ((c & 2) ? (TJ - 1) : 0));
        const float ck_ = (float)(k0 + ((c & 4) ? (TK - 1) : 0));
        const float di = t0 * ci_ + t1 * cj_ + t2  * ck_ + t3;
        const float dj = t4 * ci_ + t5 * cj_ + t6  * ck_ + t7;
        const float dk = t8 * ci_ + t9 * cj_ + t10 * ck_ + t11;
        mni = fminf(mni, di); mxi = fmaxf(mxi, di);
        mnj = fminf(mnj, dj); mxj = fmaxf(mxj, dj);
        mnk = fminf(mnk, dk); mxk = fmaxf(mxk, dk);
    }
    // Interior test: clamps can't engage, ok always true (margin 1.0 >>
    // 1e-4 incremental-rounding drift of per-voxel coords vs corner bound).
    const bool interior =
        (mni >= 0.5f) & (mxi <= 253.5f) &
        (mnj >= 0.5f) & (mxj <= 253.5f) &
        (mnk >= 0.5f) & (mxk <= 253.5f);

    int lo_i = (int)fminf(fmaxf(mni, 0.0f), 255.0f);
    int hi_i = (int)fminf(fmaxf(mxi, 0.0f), 255.0f);
    int lo_j = (int)fminf(fmaxf(mnj, 0.0f), 255.0f);
    int hi_j = (int)fminf(fmaxf(mxj, 0.0f), 255.0f);
    int lo_k = (int)fminf(fmaxf(mnk, 0.0f), 255.0f);
    int hi_k = (int)fminf(fmaxf(mxk, 0.0f), 255.0f);
    lo_i = min(max(lo_i - 1, 0), 252);
    lo_j = min(max(lo_j - 1, 0), 252);
    lo_k = min(max(lo_k - 1, 0), 252);
    hi_i = min(max(hi_i + 2, lo_i + 3), 255);
    hi_j = min(max(hi_j + 2, lo_j + 3), 255);
    hi_k = min(max(hi_k + 2, lo_k + 3), 255);
    const int Si = hi_i - lo_i + 1;
    const int Sj = hi_j - lo_j + 1;
    int Sk  = hi_k - lo_k + 1;
    int SkL = (Sk + 3) & ~3;             // staged k floats (16B chunk grid)
    if (lo_k + SkL > 256) {              // k-window shift guard (R13)
        lo_k = 256 - SkL;
        Sk = hi_k - lo_k + 1;
        SkL = (Sk + 3) & ~3;
    }
    int Pk = SkL;
    if ((Pk & 7) == 0) Pk += 4;          // Pk == 4 (mod 8)
    const int SjPk = Sj * Pk;
    const bool fits = (Si * SjPk <= LDSF) && (Sj <= 16) && (Sk <= 32);

    if (fits) {
        // -------- stage box into LDS (verbatim R13) ------------------------
        {
            const int lj  = tid & 15;            // j-row
            const int c4  = (tid >> 4) & 7;      // 4-float chunk id
            const int li0 = tid >> 7;            // 0/1 -> i-plane parity
            const int kk  = c4 << 2;
            if (lj < Sj && kk < SkL) {
                const float* gp = vol + ((lo_i + li0) << 16)
                                      + ((lo_j + lj) << 8) + lo_k + kk;
                float* sp = sv + (li0 * Sj + lj) * Pk + kk;
                int li = li0;
                for (; li + 2 < Si; li += 4) {
                    const f4v a = *(const f4u*)gp;
                    const f4v b = *(const f4u*)(gp + (2 << 16));
                    *(f4u*)sp = a;
                    *(f4u*)(sp + 2 * SjPk) = b;
                    gp += 4 << 16;
                    sp += 4 * SjPk;
                }
                for (; li < Si; li += 2) {
                    *(f4u*)sp = *(const f4u*)gp;
                    gp += 2 << 16;
                    sp += 2 * SjPk;
                }
            }
        }
        __syncthreads();

        const float gi_ = (float)(i0 + ihalf * 4);
        float di_ = t0 * gi_ + t1 * gj + t2  * gk + t3;
        float dj_ = t4 * gi_ + t5 * gj + t6  * gk + t7;
        float dk_ = t8 * gi_ + t9 * gj + t10 * gk + t11;

        if (interior) {
            // ---- interior fast path: no clamps, no ok, no min -------------
#pragma unroll
            for (int s_ = 0; s_ < 4; ++s_) {
                const int fi = (int)di_;
                const int fj = (int)dj_;
                const int fk = (int)dk_;
                const float wi = di_ - (float)fi;
                const float wj = dj_ - (float)fj;
                const float wk = dk_ - (float)fk;

                const int o_fi = (fi - lo_i) * SjPk;
                const int o_fj = (fj - lo_j) * Pk;
                const int pl = fk - lo_k;

                const f2v v0 = *(const f2u*)(sv + o_fi + o_fj + pl);
                const f2v v1 = *(const f2u*)(sv + o_fi + o_fj + Pk + pl);
                const f2v v2 = *(const f2u*)(sv + o_fi + SjPk + o_fj + pl);
                const f2v v3 = *(const f2u*)(sv + o_fi + SjPk + o_fj + Pk + pl);

                const float c00 = v0.x + (v0.y - v0.x) * wk;
                const float c01 = v1.x + (v1.y - v1.x) * wk;
                const float c10 = v2.x + (v2.y - v2.x) * wk;
                const float c11 = v3.x + (v3.y - v3.x) * wk;
                const float c0  = c00 + (c01 - c00) * wj;
                const float c1  = c10 + (c11 - c10) * wj;
                const float val = c0 + (c1 - c0) * wi;

                __builtin_nontemporal_store(val,
                    &out[out_base + ((ihalf * 4 + s_) << 16)]);

                di_ += t0; dj_ += t4; dk_ += t8;
            }
        } else {
            // ---- edge tile: verbatim R13 consume --------------------------
#pragma unroll
            for (int s_ = 0; s_ < 4; ++s_) {
                const float cdi = fminf(fmaxf(di_, 0.0f), (float)(DD - 1));
                const float cdj = fminf(fmaxf(dj_, 0.0f), (float)(HH - 1));
                const float cdk = fminf(fmaxf(dk_, 0.0f), (float)(WW - 1));
                const int fi = (int)cdi;
                const int fj = (int)cdj;
                const int fk = (int)cdk;
                const int ci = min(fi + 1, DD - 1);
                const int cj = min(fj + 1, HH - 1);
                const int pk = min(fk, WW - 2);
                const float wi = cdi - (float)fi;
                const float wj = cdj - (float)fj;
                const float wk = cdk - (float)pk;
                const bool ok_ = (di_ >= 0.0f) & (di_ <= (float)(DD - 1)) &
                                 (dj_ >= 0.0f) & (dj_ <= (float)(HH - 1)) &
                                 (dk_ >= 0.0f) & (dk_ <= (float)(WW - 1));

                const int o_fi = (fi - lo_i) * SjPk;
                const int o_ci = (ci - lo_i) * SjPk;
                const int o_fj = (fj - lo_j) * Pk;
                const int o_cj = (cj - lo_j) * Pk;
                const int pl = pk - lo_k;

                const f2v v0 = *(const f2u*)(sv + o_fi + o_fj + pl);
                const f2v v1 = *(const f2u*)(sv + o_fi + o_cj + pl);
                const f2v v2 = *(const f2u*)(sv + o_ci + o_fj + pl);
                const f2v v3 = *(const f2u*)(sv + o_ci + o_cj + pl);

                const float c00 = v0.x + (v0.y - v0.x) * wk;
                const float c01 = v1.x + (v1.y - v1.x) * wk;
                const float c10 = v2.x + (v2.y - v2.x) * wk;
                const float c11 = v3.x + (v3.y - v3.x) * wk;
                const float c0  = c00 + (c01 - c00) * wj;
                const float c1  = c10 + (c11 - c10) * wj;
                const float val = c0 + (c1 - c0) * wi;

                __builtin_nontemporal_store(ok_ ? val : 0.0f,
                    &out[out_base + ((ihalf * 4 + s_) << 16)]);

                di_ += t0; dj_ += t4; dk_ += t8;
            }
        }
    } else {
        // -------- fallback: per-voxel global gather (verbatim R13) ---------
        const float gi_ = (float)(i0 + ihalf * 4);
        float di_ = t0 * gi_ + t1 * gj + t2  * gk + t3;
        float dj_ = t4 * gi_ + t5 * gj + t6  * gk + t7;
        float dk_ = t8 * gi_ + t9 * gj + t10 * gk + t11;
#pragma unroll
        for (int s_ = 0; s_ < 4; ++s_) {
            const float cdi = fminf(fmaxf(di_, 0.0f), (float)(DD - 1));
            const float cdj = fminf(fmaxf(dj_, 0.0f), (float)(HH - 1));
            const float cdk = fminf(fmaxf(dk_, 0.0f), (float)(WW - 1));
            const int fi = (int)cdi;
            const int fj = (int)cdj;
            const int fk = (int)cdk;
            const int ci = min(fi + 1, DD - 1);
            const int cj = min(fj + 1, HH - 1);
            const int pk = min(fk, WW - 2);
            const float wi = cdi - (float)fi;
            const float wj = cdj - (float)fj;
            const float wk = cdk - (float)pk;
            const bool ok_ = (di_ >= 0.0f) & (di_ <= (float)(DD - 1)) &
                             (dj_ >= 0.0f) & (dj_ <= (float)(HH - 1)) &
                             (dk_ >= 0.0f) & (dk_ <= (float)(WW - 1));

            const int fi_o = fi << 16, ci_o = ci << 16;
            const int fj_o = fj << 8,  cj_o = cj << 8;
            const f2v v0 = *(const f2u*)(vol + (fi_o + fj_o + pk));
            const f2v v1 = *(const f2u*)(vol + (fi_o + cj_o + pk));
            const f2v v2 = *(const f2u*)(vol + (ci_o + fj_o + pk));
            const f2v v3 = *(const f2u*)(vol + (ci_o + cj_o + pk));

            const float c00 = v0.x + (v0.y - v0.x) * wk;
            const float c01 = v1.x + (v1.y - v1.x) * wk;
            const float c10 = v2.x + (v2.y - v2.x) * wk;
            const float c11 = v3.x + (v3.y - v3.x) * wk;
            const float c0  = c00 + (c01 - c00) * wj;
            const float c1  = c10 + (c11 - c10) * wj;
            const float val = c0 + (c1 - c0) * wi;

            __builtin_nontemporal_store(ok_ ? val : 0.0f,
                &out[out_base + ((ihalf * 4 + s_) << 16)]);

            di_ += t0; dj_ += t4; dk_ += t8;
        }
    }
}

extern "C" void kernel_launch(void* const* d_in, const int* in_sizes, int n_in,
                              void* d_out, int out_size, void* d_ws, size_t ws_size,
                              hipStream_t stream) {
    const float* image_targ  = (const float*)d_in[0];
    const float* angle       = (const float*)d_in[1];
    const float* translation = (const float*)d_in[2];
    const float* ref_v2r     = (const float*)d_in[3];
    const float* flo_v2r     = (const float*)d_in[4];
    const float* cog         = (const float*)d_in[5];
    float* out = (float*)d_out;
    float* Tws = (float*)d_ws;   // 12 floats

    compute_T_kernel<<<1, 64, 0, stream>>>(angle, translation, ref_v2r,
                                           flo_v2r, cog, Tws);
    // 16384 blocks: 8 bricks x (16 i-tiles x 16 j-tiles x 8 k-tiles).
    warp_kernel<<<(DD / TI) * (HH / TJ) * (WW / TK), 256, 0, stream>>>(
        image_targ, Tws, out);
}